// Round 1
// 447.718 us; speedup vs baseline: 1.0843x; 1.0843x over previous
//
#include <hip/hip_runtime.h>

// out[b,c,p] = alpha[slot[b,p], c] * x[b,c,p] + beta[slot[b,p], c]
//   x: [B=32, C=2048, HW=1024] fp32, slot: [B, 1024] int32 in [0,256)
//   alpha/beta: [256, 2048] fp32
//
// Block = (image b, channel group of 8). 256 threads, 8192 blocks.
// Changes vs previous round (159 us -> target ~110 us):
//  - STAGING LOADS ISSUED FIRST: vmcnt is in-order, so the ds_write of the
//    staged rows now waits only on the L2-latency table loads (vmcnt(8)),
//    not on draining the HBM-latency x loads (old order forced vmcnt(0)
//    before the barrier).
//  - 8 channels/block: 32 KB streamed per block (2x MLP per wave, half the
//    blocks/barriers/stagings per byte).
//  - Per-channel scalar LDS layout lds[ch][slot]: gather bank = slot % 32
//    (all 32 banks, ~2-way random aliasing = free) instead of f4 rows at
//    16 B stride (only 8 bank groups -> ~3x conflicted ds_read_b128).

typedef float  f4 __attribute__((ext_vector_type(4)));
typedef int    i4 __attribute__((ext_vector_type(4)));

#define CH   2048
#define HW   1024
#define NS   256
#define CPB  8              // channels per block
#define NCG  (CH / CPB)     // 256 channel-group blocks per image

__global__ __launch_bounds__(256, 4) void fa_kernel(
    const float* __restrict__ x,
    const int*   __restrict__ slot,
    const float* __restrict__ alpha,
    const float* __restrict__ beta,
    float*       __restrict__ out)
{
    __shared__ float lds_a[CPB][NS];   // 8 KB, bank = slot % 32
    __shared__ float lds_b[CPB][NS];   // 8 KB

    const int cg = blockIdx.x & (NCG - 1);
    const int b  = blockIdx.x >> 8;          // /256
    const int c0 = cg * CPB;
    const int t  = threadIdx.x;
    const int p  = t << 2;

    // ---- issue order matters: L2-latency staging loads FIRST ----
    // slot ids for this thread's 4 pixels (coalesced int4)
    const i4 s = *(const i4*)(slot + b * HW + p);

    // cooperative table staging: thread t owns slot-row t (L2 hits)
    const f4 ar0 = *(const f4*)(alpha + (size_t)t * CH + c0);
    const f4 ar1 = *(const f4*)(alpha + (size_t)t * CH + c0 + 4);
    const f4 br0 = *(const f4*)(beta  + (size_t)t * CH + c0);
    const f4 br1 = *(const f4*)(beta  + (size_t)t * CH + c0 + 4);

    // streamed x AFTER staging loads: these stay in flight across the
    // barrier (nontemporal: don't evict the L2-resident tables)
    const size_t base = ((size_t)b * CH + c0) * HW + p;
    f4 xv[CPB];
#pragma unroll
    for (int k = 0; k < CPB; ++k)
        xv[k] = __builtin_nontemporal_load((const f4*)(x + base + (size_t)k * HW));

    // transpose rows into per-channel scalar arrays (stride-1 writes, no
    // conflicts: 2 lanes/bank)
#pragma unroll
    for (int k = 0; k < 4; ++k) {
        lds_a[k][t]     = ar0[k];
        lds_a[4 + k][t] = ar1[k];
        lds_b[k][t]     = br0[k];
        lds_b[4 + k][t] = br1[k];
    }

    __syncthreads();

    // per-(pixel,channel) scalar gathers: bank = slot % 32, well spread
#pragma unroll
    for (int k = 0; k < CPB; ++k) {
        const float a0 = lds_a[k][s.x], a1 = lds_a[k][s.y],
                    a2 = lds_a[k][s.z], a3 = lds_a[k][s.w];
        const float b0 = lds_b[k][s.x], b1 = lds_b[k][s.y],
                    b2 = lds_b[k][s.z], b3 = lds_b[k][s.w];
        f4 o;
        o[0] = a0 * xv[k][0] + b0;
        o[1] = a1 * xv[k][1] + b1;
        o[2] = a2 * xv[k][2] + b2;
        o[3] = a3 * xv[k][3] + b3;
        __builtin_nontemporal_store(o, (f4*)(out + base + (size_t)k * HW));
    }
}

extern "C" void kernel_launch(void* const* d_in, const int* in_sizes, int n_in,
                              void* d_out, int out_size, void* d_ws, size_t ws_size,
                              hipStream_t stream) {
    const float* x     = (const float*)d_in[0];
    const int*   slot  = (const int*)d_in[1];
    const float* alpha = (const float*)d_in[2];
    const float* beta  = (const float*)d_in[3];
    float*       out   = (float*)d_out;

    const int B = in_sizes[0] / (CH * HW);   // 32
    dim3 grid(B * NCG);                       // 8192 blocks
    dim3 block(256);
    fa_kernel<<<grid, block, 0, stream>>>(x, slot, alpha, beta, out);
}

// Round 2
// 429.635 us; speedup vs baseline: 1.1299x; 1.0421x over previous
//
#include <hip/hip_runtime.h>

// out[b,c,p] = alpha[slot[b,p], c] * x[b,c,p] + beta[slot[b,p], c]
//   x: [B=32, C=2048, HW=1024] fp32, slot: [B, 1024] int32 in [0,256)
//   alpha/beta: [256, 2048] fp32
//
// Block = (image group of 4, channel group of 8). 256 threads, 2048 blocks.
// Changes vs previous round (fa ~119 us -> target ~105 us):
//  - IMAGE LOOP: each block stages its 16 KB table slice ONCE and streams
//    x for 4 images (128 KB). Table staging traffic drops 128 MB -> 32 MB
//    (the 4 MB combined table exactly fills one XCD's 4 MiB L2 and was
//    contending with the x/out streams -> partial HBM re-fetch).
//  - Barriers 8192 -> 2048 (one per block, before the image loop).
//  - Same per-channel scalar LDS layout (bank = slot % 32, ~2-way random
//    aliasing = free) and staging-loads-first vmcnt ordering as R1.

typedef float  f4 __attribute__((ext_vector_type(4)));
typedef int    i4 __attribute__((ext_vector_type(4)));

#define CH   2048
#define HW   1024
#define NS   256
#define CPB  8              // channels per block
#define NCG  (CH / CPB)     // 256 channel-group blocks
#define IPB  4              // images per block

__global__ __launch_bounds__(256, 4) void fa_kernel(
    const float* __restrict__ x,
    const int*   __restrict__ slot,
    const float* __restrict__ alpha,
    const float* __restrict__ beta,
    float*       __restrict__ out)
{
    __shared__ float lds_a[CPB][NS];   // 8 KB, bank = slot % 32
    __shared__ float lds_b[CPB][NS];   // 8 KB

    const int cg = blockIdx.x & (NCG - 1);
    const int bg = blockIdx.x >> 8;          // /NCG
    const int b0 = bg * IPB;
    const int c0 = cg * CPB;
    const int t  = threadIdx.x;
    const int p  = t << 2;

    // ---- staging loads first: vmcnt is in-order, so the ds_writes below
    // wait only on these L2-latency loads, not on the x stream ----
    const f4 ar0 = *(const f4*)(alpha + (size_t)t * CH + c0);
    const f4 ar1 = *(const f4*)(alpha + (size_t)t * CH + c0 + 4);
    const f4 br0 = *(const f4*)(beta  + (size_t)t * CH + c0);
    const f4 br1 = *(const f4*)(beta  + (size_t)t * CH + c0 + 4);

    // transpose rows into per-channel scalar arrays (stride-1, conflict-free)
#pragma unroll
    for (int k = 0; k < 4; ++k) {
        lds_a[k][t]     = ar0[k];
        lds_a[4 + k][t] = ar1[k];
        lds_b[k][t]     = br0[k];
        lds_b[4 + k][t] = br1[k];
    }

    __syncthreads();

    // ---- stream IPB images through the resident table ----
#pragma unroll
    for (int i = 0; i < IPB; ++i) {
        const int b = b0 + i;

        // slot ids for this thread's 4 pixels (coalesced int4, L2-hot)
        const i4 s = *(const i4*)(slot + (size_t)b * HW + p);

        const size_t base = ((size_t)b * CH + c0) * HW + p;
        f4 xv[CPB];
#pragma unroll
        for (int k = 0; k < CPB; ++k)
            xv[k] = __builtin_nontemporal_load((const f4*)(x + base + (size_t)k * HW));

        // per-(pixel,channel) scalar gathers: bank = slot % 32, well spread
#pragma unroll
        for (int k = 0; k < CPB; ++k) {
            const float a0 = lds_a[k][s.x], a1 = lds_a[k][s.y],
                        a2 = lds_a[k][s.z], a3 = lds_a[k][s.w];
            const float b0v = lds_b[k][s.x], b1v = lds_b[k][s.y],
                        b2v = lds_b[k][s.z], b3v = lds_b[k][s.w];
            f4 o;
            o[0] = a0 * xv[k][0] + b0v;
            o[1] = a1 * xv[k][1] + b1v;
            o[2] = a2 * xv[k][2] + b2v;
            o[3] = a3 * xv[k][3] + b3v;
            __builtin_nontemporal_store(o, (f4*)(out + base + (size_t)k * HW));
        }
    }
}

extern "C" void kernel_launch(void* const* d_in, const int* in_sizes, int n_in,
                              void* d_out, int out_size, void* d_ws, size_t ws_size,
                              hipStream_t stream) {
    const float* x     = (const float*)d_in[0];
    const int*   slot  = (const int*)d_in[1];
    const float* alpha = (const float*)d_in[2];
    const float* beta  = (const float*)d_in[3];
    float*       out   = (float*)d_out;

    const int B = in_sizes[0] / (CH * HW);   // 32
    dim3 grid((B / IPB) * NCG);               // 2048 blocks
    dim3 block(256);
    fa_kernel<<<grid, block, 0, stream>>>(x, slot, alpha, beta, out);
}